// Round 1
// baseline (24477.711 us; speedup 1.0000x reference)
//
#include <hip/hip_runtime.h>
#include <stdint.h>

#define IN_DIM 256
#define HID 512
#define OUT_DIM 128
#define BT 64
#define NSTEPS 40

typedef float f32x4 __attribute__((ext_vector_type(4)));
typedef __bf16 bf16x8 __attribute__((ext_vector_type(8)));

static __device__ __forceinline__ unsigned short f2bf(float f) {
  union { float f; uint32_t u; } v; v.f = f;
  uint32_t r = v.u + 0x7FFFu + ((v.u >> 16) & 1u);  // RNE
  return (unsigned short)(r >> 16);
}
static __device__ __forceinline__ float bf2f(unsigned short b) {
  union { uint32_t u; float f; } v; v.u = ((uint32_t)b) << 16;
  return v.f;
}
static __device__ __forceinline__ float tanh_fast(float x) {
  const float ax = fabsf(x);
  const float e = __expf(-2.0f * ax);
  float t = __fdividef(1.0f - e, 1.0f + e);
  return copysignf(t, x);
}

// byte address of bf16 element (m, n) in the swizzled 64x512 A-operand LDS tile.
// Row stride 1024 B (no pad); 16B chunks XOR-swizzled by (m&7) so A-fragment
// reads (lanes 0..15 hit rows 0..15 at one chunk) spread across all banks
// (2-way max aliasing = free, m136).
static __device__ __forceinline__ int lds_ea(int m, int n) {
  return m * 1024 + ((((n >> 3) ^ (m & 7)) << 4)) + ((n & 7) << 1);
}

// C[m][n] += sum_k A[m][k] * B_src[n][k];  A from LDS (swizzled), B from packed
// fragment stream. Wave w owns columns [64w, 64w+64). acc is 4x4 tiles of 16x16.
template <int NKSEG>
static __device__ __forceinline__ void mm_tiles(const __bf16* __restrict__ Bp,
                                                const char* lds, int w, int lane,
                                                f32x4 acc[4][4]) {
  const int l15 = lane & 15;
  const int q = lane >> 4;
#pragma unroll
  for (int ks = 0; ks < NKSEG; ++ks) {
    bf16x8 a[4];
#pragma unroll
    for (int tm = 0; tm < 4; ++tm) {
      const int m = (tm << 4) + l15;  // A layout: row = lane&15, k = q*8+j
      const int addr = m * 1024 + (((((ks << 2) + q) ^ (m & 7)) << 4));
      a[tm] = *(const bf16x8*)(lds + addr);
    }
#pragma unroll
    for (int tn = 0; tn < 4; ++tn) {
      const bf16x8 b = *(const bf16x8*)(
          Bp + (size_t)((((w << 2) + tn) * NKSEG + ks) * 64 + lane) * 8);
#pragma unroll
      for (int tm = 0; tm < 4; ++tm)
        acc[tm][tn] =
            __builtin_amdgcn_mfma_f32_16x16x32_bf16(a[tm], b, acc[tm][tn], 0, 0, 0);
    }
  }
}

__global__ __launch_bounds__(512, 2) void liq_main(
    const float* __restrict__ x, const float* __restrict__ bx,
    const float* __restrict__ bvec, const float* __restrict__ tau,
    const float* __restrict__ bfh, const __bf16* __restrict__ Wx_p,
    const __bf16* __restrict__ U_p, const __bf16* __restrict__ W_p,
    const __bf16* __restrict__ Wf_p, float* __restrict__ out) {
  __shared__ __align__(16) char lds[BT * 1024];  // 64 KB A-operand buffer
  const int tid = threadIdx.x;
  const int w = tid >> 6;
  const int lane = tid & 63;
  const int l15 = lane & 15;
  const int q = lane >> 4;
  const int row0 = blockIdx.x * BT;

  // ---- stage x tile (64 x 256 fp32) into LDS as bf16 A-layout ----
  {
    const float4* x4 = (const float4*)(x + (size_t)row0 * IN_DIM);
#pragma unroll
    for (int it = 0; it < (BT * IN_DIM / 4) / 512; ++it) {
      const int id = tid + it * 512;
      const float4 v = x4[id];
      const int m = id >> 6;          // 64 float4 per row
      const int c = (id & 63) << 2;   // starting column (multiple of 4)
      uint2 pk;
      pk.x = (uint32_t)f2bf(v.x) | ((uint32_t)f2bf(v.y) << 16);
      pk.y = (uint32_t)f2bf(v.z) | ((uint32_t)f2bf(v.w) << 16);
      *(uint2*)(lds + lds_ea(m, c)) = pk;  // (c&7) in {0,4} -> 8B aligned
    }
  }

  // per-wave column constants: this lane touches columns n = 64w + 16tn + l15
  float itau[4], bxv[4], bv[4];
#pragma unroll
  for (int tn = 0; tn < 4; ++tn) {
    const int n = (w << 6) + (tn << 4) + l15;
    itau[tn] = 1.0f / tau[n];
    bxv[tn] = bx[n];
    bv[tn] = bvec[n];
  }
  __syncthreads();

  // ---- u = x @ Wx^T + bx ----
  f32x4 acc[4][4];
#pragma unroll
  for (int tm = 0; tm < 4; ++tm)
#pragma unroll
    for (int tn = 0; tn < 4; ++tn)
      acc[tm][tn] = (f32x4){bxv[tn], bxv[tn], bxv[tn], bxv[tn]};
  mm_tiles<IN_DIM / 32>(Wx_p, lds, w, lane, acc);

  float h[64], S[64];
#pragma unroll
  for (int tm = 0; tm < 4; ++tm)
#pragma unroll
    for (int tn = 0; tn < 4; ++tn)
#pragma unroll
      for (int r = 0; r < 4; ++r)
        h[(((tm << 2) + tn) << 2) + r] = acc[tm][tn][r];

  __syncthreads();  // all waves done reading x region before overwrite
#pragma unroll
  for (int tm = 0; tm < 4; ++tm)
#pragma unroll
    for (int tn = 0; tn < 4; ++tn)
#pragma unroll
      for (int r = 0; r < 4; ++r) {
        const int m = (tm << 4) + (q << 2) + r;  // C layout: row = 4q+r (+16tm)
        const int n = (w << 6) + (tn << 4) + l15;
        *(unsigned short*)(lds + lds_ea(m, n)) = f2bf(acc[tm][tn][r]);
      }
  __syncthreads();

  // ---- drive = u @ U^T + b (A buffer now holds u = h0, kept for step 0) ----
#pragma unroll
  for (int tm = 0; tm < 4; ++tm)
#pragma unroll
    for (int tn = 0; tn < 4; ++tn)
      acc[tm][tn] = (f32x4){bv[tn], bv[tn], bv[tn], bv[tn]};
  mm_tiles<HID / 32>(U_p, lds, w, lane, acc);

  uint32_t drv[32];  // drive, bf16-packed 2/VGPR, C layout
#pragma unroll
  for (int tm = 0; tm < 4; ++tm)
#pragma unroll
    for (int tn = 0; tn < 4; ++tn)
#pragma unroll
      for (int rp = 0; rp < 2; ++rp)
        drv[(((tm << 2) + tn) << 1) + rp] =
            (uint32_t)f2bf(acc[tm][tn][2 * rp]) |
            ((uint32_t)f2bf(acc[tm][tn][2 * rp + 1]) << 16);

  const float dt = 1.0f / NSTEPS;
  const float hdt = 0.5f * dt;
  const float dt6 = dt / 6.0f;

  for (int st = 0; st < NSTEPS; ++st) {
    for (int e = 0; e < 4; ++e) {  // k1..k4; NOT unrolled (I-cache)
      // acc <- drive (unpack bf16 pairs)
#pragma unroll
      for (int tm = 0; tm < 4; ++tm)
#pragma unroll
        for (int tn = 0; tn < 4; ++tn)
#pragma unroll
          for (int rp = 0; rp < 2; ++rp) {
            const uint32_t d = drv[(((tm << 2) + tn) << 1) + rp];
            union { uint32_t u; float f; } lo, hi;
            lo.u = d << 16;
            hi.u = d & 0xFFFF0000u;
            acc[tm][tn][2 * rp] = lo.f;
            acc[tm][tn][2 * rp + 1] = hi.f;
          }
      mm_tiles<HID / 32>(W_p, lds, w, lane, acc);  // acc = h_in@W^T + drive

      const float wk = (e == 1 || e == 2) ? 2.0f : 1.0f;
      const float cn = (e < 2) ? hdt : ((e == 2) ? dt : dt6);
#pragma unroll
      for (int tm = 0; tm < 4; ++tm)
#pragma unroll
        for (int tn = 0; tn < 4; ++tn)
#pragma unroll
          for (int r = 0; r < 4; ++r) {
            const int idx = (((tm << 2) + tn) << 2) + r;
            const int m = (tm << 4) + (q << 2) + r;
            const int n = (w << 6) + (tn << 4) + l15;
            const float t = tanh_fast(acc[tm][tn][r]);
            float hin = h[idx];  // e==0: exact fp32 state
            if (e != 0)          // k2..k4: read back the staged h_tmp (bf16)
              hin = bf2f(*(const unsigned short*)(lds + lds_ea(m, n)));
            const float k = (t - hin) * itau[tn];
            const float Sv = (e == 0) ? k : (S[idx] + wk * k);
            S[idx] = Sv;
            const float nxt = h[idx] + cn * ((e == 3) ? Sv : k);
            if (e == 3) h[idx] = nxt;  // RK4 state update
            acc[tm][tn][r] = nxt;      // reuse acc as staging for LDS write
          }
      __syncthreads();  // all LDS reads (A frags + h_in) complete
#pragma unroll
      for (int tm = 0; tm < 4; ++tm)
#pragma unroll
        for (int tn = 0; tn < 4; ++tn)
#pragma unroll
          for (int r = 0; r < 4; ++r) {
            const int m = (tm << 4) + (q << 2) + r;
            const int n = (w << 6) + (tn << 4) + l15;
            *(unsigned short*)(lds + lds_ea(m, n)) = f2bf(acc[tm][tn][r]);
          }
      __syncthreads();  // next A operand visible to all waves
    }
  }

  // ---- head: out = h_T @ Wf^T + bf (final h is in LDS; wave w -> 16 cols) ----
  {
    const float bfv = bfh[(w << 4) + l15];
    f32x4 acc2[4];
#pragma unroll
    for (int tm = 0; tm < 4; ++tm) acc2[tm] = (f32x4){bfv, bfv, bfv, bfv};
#pragma unroll
    for (int ks = 0; ks < HID / 32; ++ks) {
      bf16x8 a[4];
#pragma unroll
      for (int tm = 0; tm < 4; ++tm) {
        const int m = (tm << 4) + l15;
        const int addr = m * 1024 + (((((ks << 2) + q) ^ (m & 7)) << 4));
        a[tm] = *(const bf16x8*)(lds + addr);
      }
      const bf16x8 b =
          *(const bf16x8*)(Wf_p + (size_t)(((w << 4) + ks) * 64 + lane) * 8);
#pragma unroll
      for (int tm = 0; tm < 4; ++tm)
        acc2[tm] = __builtin_amdgcn_mfma_f32_16x16x32_bf16(a[tm], b, acc2[tm], 0, 0, 0);
    }
#pragma unroll
    for (int tm = 0; tm < 4; ++tm)
#pragma unroll
      for (int r = 0; r < 4; ++r) {
        const int m = (tm << 4) + (q << 2) + r;
        out[(size_t)(row0 + m) * OUT_DIM + (w << 4) + l15] = acc2[tm][r];
      }
  }
}

// Pack row-major fp32 weight [N][K] into bf16 B-fragment stream:
// dst[((nt*KSEG + ks)*64 + lane)*8 + j] = W[nt*16 + (lane&15)][ks*32 + (lane>>4)*8 + j]
// so the kernel's B-frag load is one coalesced global_load_dwordx4 per wave.
__global__ void pack_bfrag(const float* __restrict__ src, __bf16* __restrict__ dst,
                           int K, int kslog, int total) {
  const int i = blockIdx.x * blockDim.x + threadIdx.x;
  if (i >= total) return;
  const int j = i & 7;
  const int lane = (i >> 3) & 63;
  const int rem = i >> 9;
  const int ks = rem & ((1 << kslog) - 1);
  const int nt = rem >> kslog;
  const int n = (nt << 4) + (lane & 15);
  const int k = (ks << 5) + ((lane >> 4) << 3) + j;
  dst[i] = (__bf16)src[n * K + k];
}

extern "C" void kernel_launch(void* const* d_in, const int* in_sizes, int n_in,
                              void* d_out, int out_size, void* d_ws, size_t ws_size,
                              hipStream_t stream) {
  const float* x = (const float*)d_in[0];
  const float* Wx = (const float*)d_in[1];
  const float* bx = (const float*)d_in[2];
  const float* W = (const float*)d_in[3];
  const float* U = (const float*)d_in[4];
  const float* b = (const float*)d_in[5];
  const float* tau = (const float*)d_in[6];
  const float* Wf = (const float*)d_in[7];
  const float* bf_ = (const float*)d_in[8];
  float* out = (float*)d_out;

  char* ws = (char*)d_ws;  // 1.375 MB used
  __bf16* W_p = (__bf16*)(ws + 0);
  __bf16* U_p = (__bf16*)(ws + (512 * 1024));
  __bf16* Wx_p = (__bf16*)(ws + (1024 * 1024));
  __bf16* Wf_p = (__bf16*)(ws + (1280 * 1024));

  pack_bfrag<<<(HID * HID) / 256, 256, 0, stream>>>(W, W_p, HID, 4, HID * HID);
  pack_bfrag<<<(HID * HID) / 256, 256, 0, stream>>>(U, U_p, HID, 4, HID * HID);
  pack_bfrag<<<(HID * IN_DIM) / 256, 256, 0, stream>>>(Wx, Wx_p, IN_DIM, 3,
                                                       HID * IN_DIM);
  pack_bfrag<<<(OUT_DIM * HID) / 256, 256, 0, stream>>>(Wf, Wf_p, HID, 4,
                                                        OUT_DIM * HID);

  liq_main<<<32768 / BT, 512, 0, stream>>>(x, bx, b, tau, bf_, Wx_p, U_p, W_p,
                                           Wf_p, out);
}

// Round 2
// 22759.235 us; speedup vs baseline: 1.0755x; 1.0755x over previous
//
#include <hip/hip_runtime.h>
#include <stdint.h>

#define IN_DIM 256
#define HID 512
#define OUT_DIM 128
#define BT 64
#define NSTEPS 40

typedef float f32x4 __attribute__((ext_vector_type(4)));
typedef __bf16 bf16x8 __attribute__((ext_vector_type(8)));

static __device__ __forceinline__ unsigned short f2bf(float f) {
  union { float f; uint32_t u; } v; v.f = f;
  uint32_t r = v.u + 0x7FFFu + ((v.u >> 16) & 1u);  // RNE
  return (unsigned short)(r >> 16);
}
static __device__ __forceinline__ float bf2f(unsigned short b) {
  union { uint32_t u; float f; } v; v.u = ((uint32_t)b) << 16;
  return v.f;
}
static __device__ __forceinline__ float tanh_fast(float x) {
  const float ax = fabsf(x);
  const float e = __expf(-2.0f * ax);
  float t = __fdividef(1.0f - e, 1.0f + e);
  return copysignf(t, x);
}

// byte address of bf16 element (m, n) in the swizzled 64x512 A-operand LDS tile.
// Row stride 1024 B; 16B chunks XOR-swizzled by (m&7): A-frag reads are 2-way
// bank-aliased max (free, m136).
static __device__ __forceinline__ int lds_ea(int m, int n) {
  return m * 1024 + ((((n >> 3) ^ (m & 7)) << 4)) + ((n & 7) << 1);
}

// C[m][n] += sum_k A[m][k] * B_src[n][k];  A from LDS (swizzled), B from packed
// fragment stream (coalesced dwordx4, L2-resident). Wave w owns cols [64w,64w+64).
template <int NKSEG>
static __device__ __forceinline__ void mm_tiles(const __bf16* __restrict__ Bp,
                                                const char* lds, int w, int lane,
                                                f32x4 acc[4][4]) {
  const int l15 = lane & 15;
  const int q = lane >> 4;
#pragma unroll
  for (int ks = 0; ks < NKSEG; ++ks) {
    bf16x8 a[4];
#pragma unroll
    for (int tm = 0; tm < 4; ++tm) {
      const int m = (tm << 4) + l15;  // A layout: row = lane&15, k = q*8+j
      const int addr = m * 1024 + (((((ks << 2) + q) ^ (m & 7)) << 4));
      a[tm] = *(const bf16x8*)(lds + addr);
    }
#pragma unroll
    for (int tn = 0; tn < 4; ++tn) {
      const bf16x8 b = *(const bf16x8*)(
          Bp + (size_t)((((w << 2) + tn) * NKSEG + ks) * 64 + lane) * 8);
#pragma unroll
      for (int tm = 0; tm < 4; ++tm)
        acc[tm][tn] =
            __builtin_amdgcn_mfma_f32_16x16x32_bf16(a[tm], b, acc[tm][tn], 0, 0, 0);
    }
  }
}

__global__ __launch_bounds__(512) __attribute__((amdgpu_waves_per_eu(2, 2)))
void liq_main(
    const float* __restrict__ x, const float* __restrict__ bx,
    const float* __restrict__ bvec, const float* __restrict__ tau,
    const float* __restrict__ bfh, const __bf16* __restrict__ Wx_p,
    const __bf16* __restrict__ U_p, const __bf16* __restrict__ W_p,
    const __bf16* __restrict__ Wf_p, float* __restrict__ out) {
  __shared__ __align__(16) char lds[BT * 1024];   // 64 KB A-operand staging
  __shared__ __align__(8) uint2 drv_lds[16 * 512]; // 64 KB drive (bf16-packed)
  const int tid = threadIdx.x;
  const int w = tid >> 6;
  const int lane = tid & 63;
  const int l15 = lane & 15;
  const int q = lane >> 4;
  const int row0 = blockIdx.x * BT;

  // ---- stage x tile (64 x 256 fp32) into LDS as bf16 A-layout ----
  {
    const float4* x4 = (const float4*)(x + (size_t)row0 * IN_DIM);
#pragma unroll
    for (int it = 0; it < (BT * IN_DIM / 4) / 512; ++it) {
      const int id = tid + it * 512;
      const float4 v = x4[id];
      const int m = id >> 6;          // 64 float4 per row
      const int c = (id & 63) << 2;   // starting column (multiple of 4)
      uint2 pk;
      pk.x = (uint32_t)f2bf(v.x) | ((uint32_t)f2bf(v.y) << 16);
      pk.y = (uint32_t)f2bf(v.z) | ((uint32_t)f2bf(v.w) << 16);
      *(uint2*)(lds + lds_ea(m, c)) = pk;  // (c&7) in {0,4} -> 8B aligned
    }
  }

  // per-wave column constants: this lane touches columns n = 64w + 16tn + l15
  float itau[4], bxv[4], bv[4];
#pragma unroll
  for (int tn = 0; tn < 4; ++tn) {
    const int n = (w << 6) + (tn << 4) + l15;
    itau[tn] = 1.0f / tau[n];
    bxv[tn] = bx[n];
    bv[tn] = bvec[n];
  }
  __syncthreads();

  // ---- u = x @ Wx^T + bx ----
  f32x4 acc[4][4];
#pragma unroll
  for (int tm = 0; tm < 4; ++tm)
#pragma unroll
    for (int tn = 0; tn < 4; ++tn)
      acc[tm][tn] = (f32x4){bxv[tn], bxv[tn], bxv[tn], bxv[tn]};
  mm_tiles<IN_DIM / 32>(Wx_p, lds, w, lane, acc);

  float h[64], S[64];
#pragma unroll
  for (int tm = 0; tm < 4; ++tm)
#pragma unroll
    for (int tn = 0; tn < 4; ++tn)
#pragma unroll
      for (int r = 0; r < 4; ++r)
        h[(((tm << 2) + tn) << 2) + r] = acc[tm][tn][r];

  __syncthreads();  // all waves done reading x region before overwrite
#pragma unroll
  for (int tm = 0; tm < 4; ++tm)
#pragma unroll
    for (int tn = 0; tn < 4; ++tn)
#pragma unroll
      for (int r = 0; r < 4; ++r) {
        const int m = (tm << 4) + (q << 2) + r;  // C layout: row = 4q+r (+16tm)
        const int n = (w << 6) + (tn << 4) + l15;
        *(unsigned short*)(lds + lds_ea(m, n)) = f2bf(acc[tm][tn][r]);
      }
  __syncthreads();

  // ---- drive = u @ U^T + b (A buffer now holds u = h0, kept for step 0) ----
#pragma unroll
  for (int tm = 0; tm < 4; ++tm)
#pragma unroll
    for (int tn = 0; tn < 4; ++tn)
      acc[tm][tn] = (f32x4){bv[tn], bv[tn], bv[tn], bv[tn]};
  mm_tiles<HID / 32>(U_p, lds, w, lane, acc);

  // drive -> LDS (bf16-packed, [tile j2][tid] layout: conflict-free b64)
#pragma unroll
  for (int tm = 0; tm < 4; ++tm)
#pragma unroll
    for (int tn = 0; tn < 4; ++tn) {
      uint2 pk;
      pk.x = (uint32_t)f2bf(acc[tm][tn][0]) | ((uint32_t)f2bf(acc[tm][tn][1]) << 16);
      pk.y = (uint32_t)f2bf(acc[tm][tn][2]) | ((uint32_t)f2bf(acc[tm][tn][3]) << 16);
      drv_lds[(((tm << 2) + tn) << 9) + tid] = pk;  // own-write / own-read
    }

  const float dt = 1.0f / NSTEPS;
  const float hdt = 0.5f * dt;
  const float dt6 = dt / 6.0f;

  for (int st = 0; st < NSTEPS; ++st) {
    for (int e = 0; e < 4; ++e) {  // k1..k4; NOT unrolled (I-cache)
      // acc <- drive (from LDS, unpack bf16 pairs)
#pragma unroll
      for (int tm = 0; tm < 4; ++tm)
#pragma unroll
        for (int tn = 0; tn < 4; ++tn) {
          const uint2 d2 = drv_lds[(((tm << 2) + tn) << 9) + tid];
          union { uint32_t u; float f; } a0, a1, a2, a3;
          a0.u = d2.x << 16;
          a1.u = d2.x & 0xFFFF0000u;
          a2.u = d2.y << 16;
          a3.u = d2.y & 0xFFFF0000u;
          acc[tm][tn] = (f32x4){a0.f, a1.f, a2.f, a3.f};
        }
      mm_tiles<HID / 32>(W_p, lds, w, lane, acc);  // acc = h_in@W^T + drive

      const float wk = (e == 1 || e == 2) ? 2.0f : 1.0f;
      const float cn = (e < 2) ? hdt : ((e == 2) ? dt : dt6);
#pragma unroll
      for (int tm = 0; tm < 4; ++tm)
#pragma unroll
        for (int tn = 0; tn < 4; ++tn)
#pragma unroll
          for (int r = 0; r < 4; ++r) {
            const int idx = (((tm << 2) + tn) << 2) + r;
            const int m = (tm << 4) + (q << 2) + r;
            const int n = (w << 6) + (tn << 4) + l15;
            const float t = tanh_fast(acc[tm][tn][r]);
            float hin = h[idx];  // e==0: exact fp32 state
            if (e != 0)          // k2..k4: read back the staged h_tmp (bf16)
              hin = bf2f(*(const unsigned short*)(lds + lds_ea(m, n)));
            const float k = (t - hin) * itau[tn];
            const float Sv = (e == 0) ? k : (S[idx] + wk * k);
            S[idx] = Sv;
            const float nxt = h[idx] + cn * ((e == 3) ? Sv : k);
            if (e == 3) h[idx] = nxt;  // RK4 state update
            acc[tm][tn][r] = nxt;      // reuse acc as staging for LDS write
          }
      __syncthreads();  // all LDS reads (A frags + h_in) complete
#pragma unroll
      for (int tm = 0; tm < 4; ++tm)
#pragma unroll
        for (int tn = 0; tn < 4; ++tn)
#pragma unroll
          for (int r = 0; r < 4; ++r) {
            const int m = (tm << 4) + (q << 2) + r;
            const int n = (w << 6) + (tn << 4) + l15;
            *(unsigned short*)(lds + lds_ea(m, n)) = f2bf(acc[tm][tn][r]);
          }
      __syncthreads();  // next A operand visible to all waves
    }
  }

  // ---- head: out = h_T @ Wf^T + bf (final h is in LDS; wave w -> 16 cols) ----
  {
    const float bfv = bfh[(w << 4) + l15];
    f32x4 acc2[4];
#pragma unroll
    for (int tm = 0; tm < 4; ++tm) acc2[tm] = (f32x4){bfv, bfv, bfv, bfv};
#pragma unroll
    for (int ks = 0; ks < HID / 32; ++ks) {
      bf16x8 a[4];
#pragma unroll
      for (int tm = 0; tm < 4; ++tm) {
        const int m = (tm << 4) + l15;
        const int addr = m * 1024 + (((((ks << 2) + q) ^ (m & 7)) << 4));
        a[tm] = *(const bf16x8*)(lds + addr);
      }
      const bf16x8 b =
          *(const bf16x8*)(Wf_p + (size_t)(((w << 4) + ks) * 64 + lane) * 8);
#pragma unroll
      for (int tm = 0; tm < 4; ++tm)
        acc2[tm] = __builtin_amdgcn_mfma_f32_16x16x32_bf16(a[tm], b, acc2[tm], 0, 0, 0);
    }
#pragma unroll
    for (int tm = 0; tm < 4; ++tm)
#pragma unroll
      for (int r = 0; r < 4; ++r) {
        const int m = (tm << 4) + (q << 2) + r;
        out[(size_t)(row0 + m) * OUT_DIM + (w << 4) + l15] = acc2[tm][r];
      }
  }
}

// Pack row-major fp32 weight [N][K] into bf16 B-fragment stream:
// dst[((nt*KSEG + ks)*64 + lane)*8 + j] = W[nt*16 + (lane&15)][ks*32 + (lane>>4)*8 + j]
__global__ void pack_bfrag(const float* __restrict__ src, __bf16* __restrict__ dst,
                           int K, int kslog, int total) {
  const int i = blockIdx.x * blockDim.x + threadIdx.x;
  if (i >= total) return;
  const int j = i & 7;
  const int lane = (i >> 3) & 63;
  const int rem = i >> 9;
  const int ks = rem & ((1 << kslog) - 1);
  const int nt = rem >> kslog;
  const int n = (nt << 4) + (lane & 15);
  const int k = (ks << 5) + ((lane >> 4) << 3) + j;
  dst[i] = (__bf16)src[n * K + k];
}

extern "C" void kernel_launch(void* const* d_in, const int* in_sizes, int n_in,
                              void* d_out, int out_size, void* d_ws, size_t ws_size,
                              hipStream_t stream) {
  const float* x = (const float*)d_in[0];
  const float* Wx = (const float*)d_in[1];
  const float* bx = (const float*)d_in[2];
  const float* W = (const float*)d_in[3];
  const float* U = (const float*)d_in[4];
  const float* b = (const float*)d_in[5];
  const float* tau = (const float*)d_in[6];
  const float* Wf = (const float*)d_in[7];
  const float* bf_ = (const float*)d_in[8];
  float* out = (float*)d_out;

  char* ws = (char*)d_ws;  // 1.375 MB used
  __bf16* W_p = (__bf16*)(ws + 0);
  __bf16* U_p = (__bf16*)(ws + (512 * 1024));
  __bf16* Wx_p = (__bf16*)(ws + (1024 * 1024));
  __bf16* Wf_p = (__bf16*)(ws + (1280 * 1024));

  pack_bfrag<<<(HID * HID) / 256, 256, 0, stream>>>(W, W_p, HID, 4, HID * HID);
  pack_bfrag<<<(HID * HID) / 256, 256, 0, stream>>>(U, U_p, HID, 4, HID * HID);
  pack_bfrag<<<(HID * IN_DIM) / 256, 256, 0, stream>>>(Wx, Wx_p, IN_DIM, 3,
                                                       HID * IN_DIM);
  pack_bfrag<<<(OUT_DIM * HID) / 256, 256, 0, stream>>>(Wf, Wf_p, HID, 4,
                                                        OUT_DIM * HID);

  liq_main<<<32768 / BT, 512, 0, stream>>>(x, bx, b, tau, bf_, Wx_p, U_p, W_p,
                                           Wf_p, out);
}

// Round 3
// 17700.336 us; speedup vs baseline: 1.3829x; 1.2858x over previous
//
#include <hip/hip_runtime.h>
#include <stdint.h>

#define IN_DIM 256
#define HID 512
#define OUT_DIM 128
#define BT 64
#define NSTEPS 40
#define TPB 1024

typedef float f32x4 __attribute__((ext_vector_type(4)));
typedef __bf16 bf16x8 __attribute__((ext_vector_type(8)));

static __device__ __forceinline__ unsigned short f2bf(float f) {
  union { float f; uint32_t u; } v; v.f = f;
  uint32_t r = v.u + 0x7FFFu + ((v.u >> 16) & 1u);  // RNE
  return (unsigned short)(r >> 16);
}
static __device__ __forceinline__ float bf2f(unsigned short b) {
  union { uint32_t u; float f; } v; v.u = ((uint32_t)b) << 16;
  return v.f;
}
static __device__ __forceinline__ float tanh_fast(float x) {
  const float ax = fabsf(x);
  const float e = __expf(-2.0f * ax);
  float t = __fdividef(1.0f - e, 1.0f + e);
  return copysignf(t, x);
}

// byte address of bf16 element (m, n) in the swizzled 64x512 A-operand LDS tile.
// Row stride 1024 B; 16B chunks XOR-swizzled by (m&7).
static __device__ __forceinline__ int lds_ea(int m, int n) {
  return m * 1024 + ((((n >> 3) ^ (m & 7)) << 4)) + ((n & 7) << 1);
}

// acc[tm][tn] += A(16tm..+16, k) * B(32w+16tn.., k) over k. A from swizzled LDS,
// B from packed fragment stream (L2-resident). Wave w owns cols [32w, 32w+32).
// B loaded first (2 frags live), A streamed per-tm: ~12 frag VGPRs live.
template <int NKSEG>
static __device__ __forceinline__ void mm_tiles(const __bf16* __restrict__ Bp,
                                                const char* lds, int w, int lane,
                                                f32x4 acc[4][2]) {
  const int l15 = lane & 15;
  const int q = lane >> 4;
#pragma unroll
  for (int ks = 0; ks < NKSEG; ++ks) {
    bf16x8 b[2];
#pragma unroll
    for (int tn = 0; tn < 2; ++tn)
      b[tn] = *(const bf16x8*)(
          Bp + (size_t)((((w << 1) + tn) * NKSEG + ks) * 64 + lane) * 8);
#pragma unroll
    for (int tm = 0; tm < 4; ++tm) {
      const int m = (tm << 4) + l15;  // A layout: row = lane&15, k = q*8+j
      const int addr = m * 1024 + (((((ks << 2) + q) ^ (m & 7)) << 4));
      const bf16x8 a = *(const bf16x8*)(lds + addr);
#pragma unroll
      for (int tn = 0; tn < 2; ++tn)
        acc[tm][tn] =
            __builtin_amdgcn_mfma_f32_16x16x32_bf16(a, b[tn], acc[tm][tn], 0, 0, 0);
    }
  }
}

__global__ __launch_bounds__(TPB, 4) void liq_main(
    const float* __restrict__ x, const float* __restrict__ bx,
    const float* __restrict__ bvec, const float* __restrict__ tau,
    const float* __restrict__ bfh, const __bf16* __restrict__ Wx_p,
    const __bf16* __restrict__ U_p, const __bf16* __restrict__ W_p,
    const __bf16* __restrict__ Wf_p, float* __restrict__ out) {
  __shared__ __align__(16) char lds[BT * 1024];    // 64 KB A-operand staging
  __shared__ __align__(8) uint2 drv_lds[8 * TPB];  // 64 KB drive (bf16-packed)
  const int tid = threadIdx.x;
  const int w = tid >> 6;    // 16 waves
  const int lane = tid & 63;
  const int l15 = lane & 15;
  const int q = lane >> 4;
  const int row0 = blockIdx.x * BT;

  // ---- stage x tile (64 x 256 fp32) into LDS as bf16 A-layout ----
  {
    const float4* x4 = (const float4*)(x + (size_t)row0 * IN_DIM);
#pragma unroll
    for (int it = 0; it < (BT * IN_DIM / 4) / TPB; ++it) {
      const int id = tid + it * TPB;
      const float4 v = x4[id];
      const int m = id >> 6;          // 64 float4 per row
      const int c = (id & 63) << 2;   // starting column (multiple of 4)
      uint2 pk;
      pk.x = (uint32_t)f2bf(v.x) | ((uint32_t)f2bf(v.y) << 16);
      pk.y = (uint32_t)f2bf(v.z) | ((uint32_t)f2bf(v.w) << 16);
      *(uint2*)(lds + lds_ea(m, c)) = pk;  // (c&7) in {0,4} -> 8B aligned
    }
  }

  // per-wave column constants: this lane touches cols n = 32w + 16tn + l15
  float itau[2], bxv[2], bv[2];
#pragma unroll
  for (int tn = 0; tn < 2; ++tn) {
    const int n = (w << 5) + (tn << 4) + l15;
    itau[tn] = 1.0f / tau[n];
    bxv[tn] = bx[n];
    bv[tn] = bvec[n];
  }
  __syncthreads();

  // ---- u = x @ Wx^T + bx ----
  f32x4 acc[4][2];
#pragma unroll
  for (int tm = 0; tm < 4; ++tm)
#pragma unroll
    for (int tn = 0; tn < 2; ++tn)
      acc[tm][tn] = (f32x4){bxv[tn], bxv[tn], bxv[tn], bxv[tn]};
  mm_tiles<IN_DIM / 32>(Wx_p, lds, w, lane, acc);

  float h[32], S[32];
#pragma unroll
  for (int tm = 0; tm < 4; ++tm)
#pragma unroll
    for (int tn = 0; tn < 2; ++tn)
#pragma unroll
      for (int r = 0; r < 4; ++r)
        h[(((tm << 1) + tn) << 2) + r] = acc[tm][tn][r];

  __syncthreads();  // all waves done reading x region before overwrite
#pragma unroll
  for (int tm = 0; tm < 4; ++tm)
#pragma unroll
    for (int tn = 0; tn < 2; ++tn)
#pragma unroll
      for (int r = 0; r < 4; ++r) {
        const int m = (tm << 4) + (q << 2) + r;  // C layout: row = 4q+r (+16tm)
        const int n = (w << 5) + (tn << 4) + l15;
        *(unsigned short*)(lds + lds_ea(m, n)) = f2bf(acc[tm][tn][r]);
      }
  __syncthreads();

  // ---- drive = u @ U^T + b (A buffer now holds u = h0, kept for step 0) ----
#pragma unroll
  for (int tm = 0; tm < 4; ++tm)
#pragma unroll
    for (int tn = 0; tn < 2; ++tn)
      acc[tm][tn] = (f32x4){bv[tn], bv[tn], bv[tn], bv[tn]};
  mm_tiles<HID / 32>(U_p, lds, w, lane, acc);

  // drive -> LDS (bf16-packed, [tile][tid] layout: own-write / own-read)
#pragma unroll
  for (int tm = 0; tm < 4; ++tm)
#pragma unroll
    for (int tn = 0; tn < 2; ++tn) {
      uint2 pk;
      pk.x = (uint32_t)f2bf(acc[tm][tn][0]) | ((uint32_t)f2bf(acc[tm][tn][1]) << 16);
      pk.y = (uint32_t)f2bf(acc[tm][tn][2]) | ((uint32_t)f2bf(acc[tm][tn][3]) << 16);
      drv_lds[(((tm << 1) + tn) << 10) + tid] = pk;
    }

  const float dt = 1.0f / NSTEPS;
  const float hdt = 0.5f * dt;
  const float dt6 = dt / 6.0f;

  for (int st = 0; st < NSTEPS; ++st) {
    for (int e = 0; e < 4; ++e) {  // k1..k4
      // acc <- drive (from LDS, unpack bf16 pairs)
#pragma unroll
      for (int tm = 0; tm < 4; ++tm)
#pragma unroll
        for (int tn = 0; tn < 2; ++tn) {
          const uint2 d2 = drv_lds[(((tm << 1) + tn) << 10) + tid];
          union { uint32_t u; float f; } a0, a1, a2, a3;
          a0.u = d2.x << 16;
          a1.u = d2.x & 0xFFFF0000u;
          a2.u = d2.y << 16;
          a3.u = d2.y & 0xFFFF0000u;
          acc[tm][tn] = (f32x4){a0.f, a1.f, a2.f, a3.f};
        }
      mm_tiles<HID / 32>(W_p, lds, w, lane, acc);  // acc = h_in@W^T + drive

      const float wk = (e == 1 || e == 2) ? 2.0f : 1.0f;
      const float cn = (e < 2) ? hdt : ((e == 2) ? dt : dt6);
#pragma unroll
      for (int tm = 0; tm < 4; ++tm)
#pragma unroll
        for (int tn = 0; tn < 2; ++tn)
#pragma unroll
          for (int r = 0; r < 4; ++r) {
            const int idx = (((tm << 1) + tn) << 2) + r;
            const int m = (tm << 4) + (q << 2) + r;
            const int n = (w << 5) + (tn << 4) + l15;
            const float t = tanh_fast(acc[tm][tn][r]);
            float hin = h[idx];  // e==0: exact fp32 state
            if (e != 0)          // k2..k4: read back the staged h_tmp (bf16)
              hin = bf2f(*(const unsigned short*)(lds + lds_ea(m, n)));
            const float k = (t - hin) * itau[tn];
            const float Sv = (e == 0) ? k : (S[idx] + wk * k);
            S[idx] = Sv;
            const float nxt = h[idx] + cn * ((e == 3) ? Sv : k);
            if (e == 3) h[idx] = nxt;  // RK4 state update
            acc[tm][tn][r] = nxt;      // reuse acc as staging for LDS write
          }
      __syncthreads();  // all LDS reads (A frags + h_in) complete
#pragma unroll
      for (int tm = 0; tm < 4; ++tm)
#pragma unroll
        for (int tn = 0; tn < 2; ++tn)
#pragma unroll
          for (int r = 0; r < 4; ++r) {
            const int m = (tm << 4) + (q << 2) + r;
            const int n = (w << 5) + (tn << 4) + l15;
            *(unsigned short*)(lds + lds_ea(m, n)) = f2bf(acc[tm][tn][r]);
          }
      __syncthreads();  // next A operand visible to all waves
    }
  }

  // ---- head: out = h_T @ Wf^T + bf (waves 0..7; wave w -> 16 out cols) ----
  if (w < 8) {
    const float bfv = bfh[(w << 4) + l15];
    f32x4 acc2[4];
#pragma unroll
    for (int tm = 0; tm < 4; ++tm) acc2[tm] = (f32x4){bfv, bfv, bfv, bfv};
#pragma unroll
    for (int ks = 0; ks < HID / 32; ++ks) {
      const bf16x8 bfr =
          *(const bf16x8*)(Wf_p + (size_t)(((w << 4) + ks) * 64 + lane) * 8);
#pragma unroll
      for (int tm = 0; tm < 4; ++tm) {
        const int m = (tm << 4) + l15;
        const int addr = m * 1024 + (((((ks << 2) + q) ^ (m & 7)) << 4));
        const bf16x8 a = *(const bf16x8*)(lds + addr);
        acc2[tm] = __builtin_amdgcn_mfma_f32_16x16x32_bf16(a, bfr, acc2[tm], 0, 0, 0);
      }
    }
#pragma unroll
    for (int tm = 0; tm < 4; ++tm)
#pragma unroll
      for (int r = 0; r < 4; ++r) {
        const int m = (tm << 4) + (q << 2) + r;
        out[(size_t)(row0 + m) * OUT_DIM + (w << 4) + l15] = acc2[tm][r];
      }
  }
}

// Pack row-major fp32 weight [N][K] into bf16 B-fragment stream:
// dst[((nt*KSEG + ks)*64 + lane)*8 + j] = W[nt*16 + (lane&15)][ks*32 + (lane>>4)*8 + j]
__global__ void pack_bfrag(const float* __restrict__ src, __bf16* __restrict__ dst,
                           int K, int kslog, int total) {
  const int i = blockIdx.x * blockDim.x + threadIdx.x;
  if (i >= total) return;
  const int j = i & 7;
  const int lane = (i >> 3) & 63;
  const int rem = i >> 9;
  const int ks = rem & ((1 << kslog) - 1);
  const int nt = rem >> kslog;
  const int n = (nt << 4) + (lane & 15);
  const int k = (ks << 5) + ((lane >> 4) << 3) + j;
  dst[i] = (__bf16)src[n * K + k];
}

extern "C" void kernel_launch(void* const* d_in, const int* in_sizes, int n_in,
                              void* d_out, int out_size, void* d_ws, size_t ws_size,
                              hipStream_t stream) {
  const float* x = (const float*)d_in[0];
  const float* Wx = (const float*)d_in[1];
  const float* bx = (const float*)d_in[2];
  const float* W = (const float*)d_in[3];
  const float* U = (const float*)d_in[4];
  const float* b = (const float*)d_in[5];
  const float* tau = (const float*)d_in[6];
  const float* Wf = (const float*)d_in[7];
  const float* bf_ = (const float*)d_in[8];
  float* out = (float*)d_out;

  char* ws = (char*)d_ws;  // 1.375 MB used
  __bf16* W_p = (__bf16*)(ws + 0);
  __bf16* U_p = (__bf16*)(ws + (512 * 1024));
  __bf16* Wx_p = (__bf16*)(ws + (1024 * 1024));
  __bf16* Wf_p = (__bf16*)(ws + (1280 * 1024));

  pack_bfrag<<<(HID * HID) / 256, 256, 0, stream>>>(W, W_p, HID, 4, HID * HID);
  pack_bfrag<<<(HID * HID) / 256, 256, 0, stream>>>(U, U_p, HID, 4, HID * HID);
  pack_bfrag<<<(HID * IN_DIM) / 256, 256, 0, stream>>>(Wx, Wx_p, IN_DIM, 3,
                                                       HID * IN_DIM);
  pack_bfrag<<<(OUT_DIM * HID) / 256, 256, 0, stream>>>(Wf, Wf_p, HID, 4,
                                                        OUT_DIM * HID);

  liq_main<<<32768 / BT, TPB, 0, stream>>>(x, bx, b, tau, bf_, Wx_p, U_p, W_p,
                                           Wf_p, out);
}

// Round 4
// 7954.337 us; speedup vs baseline: 3.0773x; 2.2252x over previous
//
#include <hip/hip_runtime.h>
#include <stdint.h>

#define IN_DIM 256
#define HID 512
#define OUT_DIM 128
#define BT 64
#define NSTEPS 40
#define TPB 1024

typedef float f32x4 __attribute__((ext_vector_type(4)));
typedef __bf16 bf16x8 __attribute__((ext_vector_type(8)));

static __device__ __forceinline__ unsigned short f2bf(float f) {
  union { float f; uint32_t u; } v; v.f = f;
  uint32_t r = v.u + 0x7FFFu + ((v.u >> 16) & 1u);  // RNE
  return (unsigned short)(r >> 16);
}
static __device__ __forceinline__ float tanh_fast(float x) {
  const float ax = fabsf(x);
  const float e = __expf(-2.0f * ax);
  float t = __fdividef(1.0f - e, 1.0f + e);
  return copysignf(t, x);
}

// byte address of bf16 element (m, n) in the swizzled 64x512 A-operand LDS
// tile. Row stride 1024 B; 16B chunks XOR-swizzled by (m&7). General form,
// used only outside the hot loop (x staging).
static __device__ __forceinline__ int lds_ea(int m, int n) {
  return m * 1024 + ((((n >> 3) ^ (m & 7)) << 4)) + ((n & 7) << 1);
}

// Hot-loop A-frag addressing, collapsed to 2 VGPRs + immediates:
//   addr(tm, ks) = (tm*16+l15)*1024 + ((((ks<<2)+q) ^ (l15&7))<<4)
//                = [A1 or A2 (ks parity)] + ks*64 + tm*16384
// with A1 = l15*1024 + ((q^(l15&3))<<4) + b2*64, A2 = same - b2*64,
// b2 = (l15>>2)&1.  (m&7 == l15&7 because tm*16 ≡ 0 mod 8.)
template <int NKSEG>
static __device__ __forceinline__ void mm_tiles(const __bf16* __restrict__ Bp,
                                                const char* lds, int A1, int A2,
                                                int w, int lane, f32x4 acc[4][2]) {
#pragma unroll
  for (int ks = 0; ks < NKSEG; ++ks) {
    bf16x8 b[2];
#pragma unroll
    for (int tn = 0; tn < 2; ++tn)
      b[tn] = *(const bf16x8*)(
          Bp + (size_t)((((w << 1) + tn) * NKSEG + ks) * 64 + lane) * 8);
    const int abase = ((ks & 1) ? A2 : A1) + (ks << 6);
#pragma unroll
    for (int tm = 0; tm < 4; ++tm) {
      const bf16x8 a = *(const bf16x8*)(lds + abase + (tm << 14));
#pragma unroll
      for (int tn = 0; tn < 2; ++tn)
        acc[tm][tn] =
            __builtin_amdgcn_mfma_f32_16x16x32_bf16(a, b[tn], acc[tm][tn], 0, 0, 0);
    }
  }
}

__global__ __launch_bounds__(TPB, 4) void liq_main(
    const float* __restrict__ x, const float* __restrict__ bx,
    const float* __restrict__ bvec, const float* __restrict__ tau,
    const float* __restrict__ bfh, const __bf16* __restrict__ Wx_p,
    const __bf16* __restrict__ U_p, const __bf16* __restrict__ W_p,
    const __bf16* __restrict__ Wf_p, float* __restrict__ out) {
  __shared__ __align__(16) char lds[BT * 1024];    // 64 KB A-operand staging
  __shared__ __align__(8) uint2 drv_lds[8 * TPB];  // 64 KB drive (bf16-packed)
  const int tid = threadIdx.x;
  const int w = tid >> 6;  // 16 waves
  const int lane = tid & 63;
  const int l15 = lane & 15;
  const int q = lane >> 4;
  const int row0 = blockIdx.x * BT;

  // A-frag address bases (2 VGPRs, loop-invariant)
  const int b2c = ((l15 >> 2) & 1) << 6;
  const int A1 = l15 * 1024 + ((q ^ (l15 & 3)) << 4) + b2c;
  const int A2 = A1 - 2 * b2c;

  // staging / h_in addresses: 8 VGPRs, tm folded into the ds offset immediate
  int addrS[2][4];
#pragma unroll
  for (int tn = 0; tn < 2; ++tn) {
    const int n = (w << 5) + (tn << 4) + l15;
    const int ch = n >> 3;
    const int lo = (n & 7) << 1;
#pragma unroll
    for (int r = 0; r < 4; ++r)
      addrS[tn][r] = (((q << 2) + r) << 10) + (((ch ^ ((q & 1) << 2) ^ r) << 4)) + lo;
  }

  // ---- stage x tile (64 x 256 fp32) into LDS as bf16 A-layout ----
  {
    const float4* x4 = (const float4*)(x + (size_t)row0 * IN_DIM);
#pragma unroll
    for (int it = 0; it < (BT * IN_DIM / 4) / TPB; ++it) {
      const int id = tid + it * TPB;
      const float4 v = x4[id];
      const int m = id >> 6;         // 64 float4 per row
      const int c = (id & 63) << 2;  // starting column (multiple of 4)
      uint2 pk;
      pk.x = (uint32_t)f2bf(v.x) | ((uint32_t)f2bf(v.y) << 16);
      pk.y = (uint32_t)f2bf(v.z) | ((uint32_t)f2bf(v.w) << 16);
      *(uint2*)(lds + lds_ea(m, c)) = pk;  // (c&7) in {0,4} -> 8B aligned
    }
  }

  // per-wave column constants: this lane touches cols n = 32w + 16tn + l15
  float itau[2], bxv[2], bv[2];
#pragma unroll
  for (int tn = 0; tn < 2; ++tn) {
    const int n = (w << 5) + (tn << 4) + l15;
    itau[tn] = 1.0f / tau[n];
    bxv[tn] = bx[n];
    bv[tn] = bvec[n];
  }
  __syncthreads();

  // ---- u = x @ Wx^T + bx ----
  f32x4 acc[4][2];
#pragma unroll
  for (int tm = 0; tm < 4; ++tm)
#pragma unroll
    for (int tn = 0; tn < 2; ++tn)
      acc[tm][tn] = (f32x4){bxv[tn], bxv[tn], bxv[tn], bxv[tn]};
  mm_tiles<IN_DIM / 32>(Wx_p, lds, A1, A2, w, lane, acc);

  float h[32];
#pragma unroll
  for (int tm = 0; tm < 4; ++tm)
#pragma unroll
    for (int tn = 0; tn < 2; ++tn)
#pragma unroll
      for (int r = 0; r < 4; ++r)
        h[(((tm << 1) + tn) << 2) + r] = acc[tm][tn][r];

  __syncthreads();  // all waves done reading x region before overwrite
#pragma unroll
  for (int tm = 0; tm < 4; ++tm)
#pragma unroll
    for (int tn = 0; tn < 2; ++tn)
#pragma unroll
      for (int r = 0; r < 4; ++r)
        *(unsigned short*)(lds + addrS[tn][r] + (tm << 14)) = f2bf(acc[tm][tn][r]);
  __syncthreads();

  // ---- drive = u @ U^T + b (A buffer now holds u = h0, kept for step 0) ----
#pragma unroll
  for (int tm = 0; tm < 4; ++tm)
#pragma unroll
    for (int tn = 0; tn < 2; ++tn)
      acc[tm][tn] = (f32x4){bv[tn], bv[tn], bv[tn], bv[tn]};
  mm_tiles<HID / 32>(U_p, lds, A1, A2, w, lane, acc);

  // drive -> LDS (bf16-packed, [tile][tid] layout: own-write / own-read)
#pragma unroll
  for (int tm = 0; tm < 4; ++tm)
#pragma unroll
    for (int tn = 0; tn < 2; ++tn) {
      uint2 pk;
      pk.x = (uint32_t)f2bf(acc[tm][tn][0]) | ((uint32_t)f2bf(acc[tm][tn][1]) << 16);
      pk.y = (uint32_t)f2bf(acc[tm][tn][2]) | ((uint32_t)f2bf(acc[tm][tn][3]) << 16);
      drv_lds[(((tm << 1) + tn) << 10) + tid] = pk;
    }

  const float dt = 1.0f / NSTEPS;
  const float hdt = 0.5f * dt;
  const float dt6 = dt / 6.0f;

  uint32_t Sp[16];  // RK4 sum S, bf16-packed 2/VGPR

  for (int st = 0; st < NSTEPS; ++st) {
    for (int e = 0; e < 4; ++e) {  // k1..k4
      // acc <- drive (from LDS, unpack bf16 pairs)
#pragma unroll
      for (int tm = 0; tm < 4; ++tm)
#pragma unroll
        for (int tn = 0; tn < 2; ++tn) {
          const uint2 d2 = drv_lds[(((tm << 1) + tn) << 10) + tid];
          union { uint32_t u; float f; } a0, a1, a2, a3;
          a0.u = d2.x << 16;
          a1.u = d2.x & 0xFFFF0000u;
          a2.u = d2.y << 16;
          a3.u = d2.y & 0xFFFF0000u;
          acc[tm][tn] = (f32x4){a0.f, a1.f, a2.f, a3.f};
        }
      mm_tiles<HID / 32>(W_p, lds, A1, A2, w, lane, acc);  // h_in@W^T + drive

      const float wk = (e == 1 || e == 2) ? 2.0f : 1.0f;
      const float cn = (e < 2) ? hdt : ((e == 2) ? dt : dt6);
#pragma unroll
      for (int tm = 0; tm < 4; ++tm)
#pragma unroll
        for (int tn = 0; tn < 2; ++tn) {
          const int ti = (tm << 1) + tn;
          float kk[4], sv[4];
#pragma unroll
          for (int r = 0; r < 4; ++r) {
            const float t = tanh_fast(acc[tm][tn][r]);
            float hin;
            if (e == 0)
              hin = h[(ti << 2) + r];  // exact fp32 state
            else {                     // staged h_tmp (bf16) from LDS
              union { uint32_t u; float f; } hv;
              hv.u = ((uint32_t)*(const unsigned short*)(lds + addrS[tn][r] +
                                                         (tm << 14)))
                     << 16;
              hin = hv.f;
            }
            kk[r] = (t - hin) * itau[tn];
          }
          if (e == 0) {
            sv[0] = kk[0]; sv[1] = kk[1]; sv[2] = kk[2]; sv[3] = kk[3];
          } else {
            const uint32_t s01 = Sp[(ti << 1)], s23 = Sp[(ti << 1) + 1];
            union { uint32_t u; float f; } t0, t1, t2, t3;
            t0.u = s01 << 16;
            t1.u = s01 & 0xFFFF0000u;
            t2.u = s23 << 16;
            t3.u = s23 & 0xFFFF0000u;
            sv[0] = t0.f + wk * kk[0];
            sv[1] = t1.f + wk * kk[1];
            sv[2] = t2.f + wk * kk[2];
            sv[3] = t3.f + wk * kk[3];
          }
          if (e < 3) {  // e==3: S dead after this eval
            Sp[(ti << 1)] = (uint32_t)f2bf(sv[0]) | ((uint32_t)f2bf(sv[1]) << 16);
            Sp[(ti << 1) + 1] =
                (uint32_t)f2bf(sv[2]) | ((uint32_t)f2bf(sv[3]) << 16);
          }
#pragma unroll
          for (int r = 0; r < 4; ++r) {
            const float nxt =
                h[(ti << 2) + r] + cn * ((e == 3) ? sv[r] : kk[r]);
            if (e == 3) h[(ti << 2) + r] = nxt;  // RK4 state update
            acc[tm][tn][r] = nxt;                // staging for LDS write
          }
        }
      __syncthreads();  // all LDS reads (A frags + h_in) complete
#pragma unroll
      for (int tm = 0; tm < 4; ++tm)
#pragma unroll
        for (int tn = 0; tn < 2; ++tn)
#pragma unroll
          for (int r = 0; r < 4; ++r)
            *(unsigned short*)(lds + addrS[tn][r] + (tm << 14)) =
                f2bf(acc[tm][tn][r]);
      __syncthreads();  // next A operand visible to all waves
    }
  }

  // ---- head: out = h_T @ Wf^T + bf (waves 0..7; wave w -> 16 out cols) ----
  if (w < 8) {
    const float bfv = bfh[(w << 4) + l15];
    f32x4 acc2[4];
#pragma unroll
    for (int tm = 0; tm < 4; ++tm) acc2[tm] = (f32x4){bfv, bfv, bfv, bfv};
#pragma unroll
    for (int ks = 0; ks < HID / 32; ++ks) {
      const bf16x8 bfr =
          *(const bf16x8*)(Wf_p + (size_t)(((w << 4) + ks) * 64 + lane) * 8);
      const int abase = ((ks & 1) ? A2 : A1) + (ks << 6);
#pragma unroll
      for (int tm = 0; tm < 4; ++tm) {
        const bf16x8 a = *(const bf16x8*)(lds + abase + (tm << 14));
        acc2[tm] = __builtin_amdgcn_mfma_f32_16x16x32_bf16(a, bfr, acc2[tm], 0, 0, 0);
      }
    }
#pragma unroll
    for (int tm = 0; tm < 4; ++tm)
#pragma unroll
      for (int r = 0; r < 4; ++r) {
        const int m = (tm << 4) + (q << 2) + r;
        out[(size_t)(row0 + m) * OUT_DIM + (w << 4) + l15] = acc2[tm][r];
      }
  }
}

// Pack row-major fp32 weight [N][K] into bf16 B-fragment stream:
// dst[((nt*KSEG + ks)*64 + lane)*8 + j] = W[nt*16 + (lane&15)][ks*32 + (lane>>4)*8 + j]
__global__ void pack_bfrag(const float* __restrict__ src, __bf16* __restrict__ dst,
                           int K, int kslog, int total) {
  const int i = blockIdx.x * blockDim.x + threadIdx.x;
  if (i >= total) return;
  const int j = i & 7;
  const int lane = (i >> 3) & 63;
  const int rem = i >> 9;
  const int ks = rem & ((1 << kslog) - 1);
  const int nt = rem >> kslog;
  const int n = (nt << 4) + (lane & 15);
  const int k = (ks << 5) + ((lane >> 4) << 3) + j;
  dst[i] = (__bf16)src[n * K + k];
}

extern "C" void kernel_launch(void* const* d_in, const int* in_sizes, int n_in,
                              void* d_out, int out_size, void* d_ws, size_t ws_size,
                              hipStream_t stream) {
  const float* x = (const float*)d_in[0];
  const float* Wx = (const float*)d_in[1];
  const float* bx = (const float*)d_in[2];
  const float* W = (const float*)d_in[3];
  const float* U = (const float*)d_in[4];
  const float* b = (const float*)d_in[5];
  const float* tau = (const float*)d_in[6];
  const float* Wf = (const float*)d_in[7];
  const float* bf_ = (const float*)d_in[8];
  float* out = (float*)d_out;

  char* ws = (char*)d_ws;  // 1.375 MB used
  __bf16* W_p = (__bf16*)(ws + 0);
  __bf16* U_p = (__bf16*)(ws + (512 * 1024));
  __bf16* Wx_p = (__bf16*)(ws + (1024 * 1024));
  __bf16* Wf_p = (__bf16*)(ws + (1280 * 1024));

  pack_bfrag<<<(HID * HID) / 256, 256, 0, stream>>>(W, W_p, HID, 4, HID * HID);
  pack_bfrag<<<(HID * HID) / 256, 256, 0, stream>>>(U, U_p, HID, 4, HID * HID);
  pack_bfrag<<<(HID * IN_DIM) / 256, 256, 0, stream>>>(Wx, Wx_p, IN_DIM, 3,
                                                       HID * IN_DIM);
  pack_bfrag<<<(OUT_DIM * HID) / 256, 256, 0, stream>>>(Wf, Wf_p, HID, 4,
                                                        OUT_DIM * HID);

  liq_main<<<32768 / BT, TPB, 0, stream>>>(x, bx, b, tau, bf_, Wx_p, U_p, W_p,
                                           Wf_p, out);
}

// Round 5
// 7809.921 us; speedup vs baseline: 3.1342x; 1.0185x over previous
//
#include <hip/hip_runtime.h>
#include <stdint.h>

#define IN_DIM 256
#define HID 512
#define OUT_DIM 128
#define BT 64
#define NSTEPS 40
#define TPB 512

typedef float f32x4 __attribute__((ext_vector_type(4)));
typedef __bf16 bf16x8 __attribute__((ext_vector_type(8)));

static __device__ __forceinline__ uint32_t f2bf(float f) {
  union { float f; uint32_t u; } v; v.f = f;
  uint32_t r = v.u + 0x7FFFu + ((v.u >> 16) & 1u);  // RNE
  return r >> 16;
}
static __device__ __forceinline__ float bflo(uint32_t u) {
  union { uint32_t u; float f; } v; v.u = u << 16; return v.f;
}
static __device__ __forceinline__ float bfhi(uint32_t u) {
  union { uint32_t u; float f; } v; v.u = u & 0xFFFF0000u; return v.f;
}
// tanh(x) = 1 - 2/(e^{2x}+1); upper clamp only (e^{2x} underflows cleanly to 0)
static __device__ __forceinline__ float tanh_fast(float x) {
  const float xc = fminf(x, 9.0f);
  const float e = __builtin_amdgcn_exp2f(xc * 2.8853900817779268f);  // 2*log2(e)
  return __builtin_fmaf(-2.0f, __builtin_amdgcn_rcpf(e + 1.0f), 1.0f);
}

// byte address of bf16 element (m=batch row, n=k/hidden col) in the swizzled
// 64x512 LDS tile. Row stride 1024 B; 16B chunks XOR-swizzled by (m&15).
static __device__ __forceinline__ int lds_ea(int m, int n) {
  return m * 1024 + ((((n >> 3) ^ (m & 15)) << 4)) + ((n & 7) << 1);
}

// Swapped-operand GEMM: D[hidden][batch] += W * h^T.
// A = weight frags (packed global stream, A-layout), B = h rows from LDS.
// acc[i][j]: i = hidden 16-tile (wave base 64w), j = batch 16-tile.
// Ap must be pre-offset: Ap + (4w*NKSEG)*512 + lane*8.
template <int NKSEG>
static __device__ __forceinline__ void mm_sw(const __bf16* __restrict__ Ap,
                                             const char* lds, int B1,
                                             f32x4 acc[4][4]) {
#pragma unroll
  for (int ks = 0; ks < NKSEG; ++ks) {
    bf16x8 wf[4];
#pragma unroll
    for (int i = 0; i < 4; ++i)
      wf[i] = *(const bf16x8*)(Ap + (size_t)(i * NKSEG + ks) * 512);
    const int ba = (B1 ^ ((ks & 3) << 6)) + ((ks >> 2) << 8);
#pragma unroll
    for (int j = 0; j < 4; ++j) {
      const bf16x8 hf = *(const bf16x8*)(lds + ba + j * 16384);
#pragma unroll
      for (int i = 0; i < 4; ++i)
        acc[i][j] =
            __builtin_amdgcn_mfma_f32_16x16x32_bf16(wf[i], hf, acc[i][j], 0, 0, 0);
    }
  }
}

__global__ __launch_bounds__(TPB, 2) void liq_main(
    const float* __restrict__ x, const float* __restrict__ bx,
    const float* __restrict__ bvec, const float* __restrict__ tau,
    const float* __restrict__ bfh, const __bf16* __restrict__ Wx_p,
    const __bf16* __restrict__ U_p, const __bf16* __restrict__ W_p,
    const __bf16* __restrict__ Wf_p, float* __restrict__ out) {
  __shared__ __align__(16) char abuf[BT * 1024];  // 64 KB operand buffer
  __shared__ __align__(8) uint2 drv[16 * TPB];    // 64 KB drive (bf16 pairs)
  const int tid = threadIdx.x;
  const int w = tid >> 6;  // 8 waves; wave owns hidden [64w, 64w+64)
  const int lane = tid & 63;
  const int l15 = lane & 15;
  const int q = lane >> 4;
  const int row0 = blockIdx.x * BT;

  // B-frag read base: addr(ks,j) = (B1 ^ ((ks&3)<<6)) + (ks>>2)*256 + j*16384
  const int B1 =
      l15 * 1024 + ((q ^ (l15 & 3)) << 4) + (((l15 >> 2) & 3) << 6);
  // stage/readback base: addr(i,j) = (A0 ^ (i<<5)) + j*16384
  // (element: batch row 16j+l15, hidden cols 64w+16i+4q .. +3, b64)
  const int chunk0 = (((q >> 1) ^ (l15 & 1))) | (((l15 >> 1) & 3) << 1) |
                     ((8 * w) ^ (l15 & 8));
  const int A0 = l15 * 1024 + ((q & 1) << 3) + (chunk0 << 4);

  // ---- stage x tile (64 x 256 fp32 -> bf16) ----
  {
    const float4* x4 = (const float4*)(x + (size_t)row0 * IN_DIM);
#pragma unroll
    for (int it = 0; it < (BT * IN_DIM / 4) / TPB; ++it) {  // 8
      const int id = tid + it * TPB;
      const float4 v = x4[id];
      const int m = id >> 6;
      const int c = (id & 63) << 2;
      uint2 pk;
      pk.x = f2bf(v.x) | (f2bf(v.y) << 16);
      pk.y = f2bf(v.z) | (f2bf(v.w) << 16);
      *(uint2*)(abuf + lds_ea(m, c)) = pk;  // (c&7) in {0,4} -> 8B aligned
    }
  }

  // itau (bf16-packed): lane's hidden cols are 64w+16i+4q+r
  uint32_t itp[8];
#pragma unroll
  for (int i = 0; i < 4; ++i) {
    const float4 tv = *(const float4*)(tau + 64 * w + 16 * i + 4 * q);
    itp[i * 2 + 0] = f2bf(1.0f / tv.x) | (f2bf(1.0f / tv.y) << 16);
    itp[i * 2 + 1] = f2bf(1.0f / tv.z) | (f2bf(1.0f / tv.w) << 16);
  }
  __syncthreads();

  // ---- u = x @ Wx^T + bx (A = Wx frags, B = x) ----
  f32x4 acc[4][4];
#pragma unroll
  for (int i = 0; i < 4; ++i) {
    const float4 b4 = *(const float4*)(bx + 64 * w + 16 * i + 4 * q);
#pragma unroll
    for (int j = 0; j < 4; ++j) acc[i][j] = (f32x4){b4.x, b4.y, b4.z, b4.w};
  }
  mm_sw<IN_DIM / 32>(Wx_p + (size_t)w * 16384 + lane * 8, abuf, B1, acc);

  float h[64];
#pragma unroll
  for (int i = 0; i < 4; ++i)
#pragma unroll
    for (int j = 0; j < 4; ++j)
#pragma unroll
      for (int r = 0; r < 4; ++r) h[(i * 4 + j) * 4 + r] = acc[i][j][r];

  __syncthreads();  // all waves done reading x before overwrite
#pragma unroll
  for (int i = 0; i < 4; ++i)
#pragma unroll
    for (int j = 0; j < 4; ++j) {
      uint2 pk;
      pk.x = f2bf(acc[i][j][0]) | (f2bf(acc[i][j][1]) << 16);
      pk.y = f2bf(acc[i][j][2]) | (f2bf(acc[i][j][3]) << 16);
      *(uint2*)(abuf + ((A0 ^ (i << 5)) + j * 16384)) = pk;
    }
  __syncthreads();

  // ---- drive = u @ U^T + b ----
#pragma unroll
  for (int i = 0; i < 4; ++i) {
    const float4 b4 = *(const float4*)(bvec + 64 * w + 16 * i + 4 * q);
#pragma unroll
    for (int j = 0; j < 4; ++j) acc[i][j] = (f32x4){b4.x, b4.y, b4.z, b4.w};
  }
  mm_sw<HID / 32>(U_p + (size_t)w * 32768 + lane * 8, abuf, B1, acc);
#pragma unroll
  for (int i = 0; i < 4; ++i)
#pragma unroll
    for (int j = 0; j < 4; ++j) {
      uint2 pk;
      pk.x = f2bf(acc[i][j][0]) | (f2bf(acc[i][j][1]) << 16);
      pk.y = f2bf(acc[i][j][2]) | (f2bf(acc[i][j][3]) << 16);
      drv[(i * 4 + j) * TPB + tid] = pk;  // own-write / own-read
    }

  const float dt = 1.0f / NSTEPS;
  const float hdt = 0.5f * dt;
  const float dt6 = dt / 6.0f;
  uint32_t Sp[32];  // RK4 sum, bf16 pairs

  for (int st = 0; st < NSTEPS; ++st) {
    for (int e = 0; e < 4; ++e) {  // k1..k4 (rolled: I-cache)
      // acc <- drive
#pragma unroll
      for (int i = 0; i < 4; ++i)
#pragma unroll
        for (int j = 0; j < 4; ++j) {
          const uint2 d = drv[(i * 4 + j) * TPB + tid];
          acc[i][j] = (f32x4){bflo(d.x), bfhi(d.x), bflo(d.y), bfhi(d.y)};
        }
      mm_sw<HID / 32>(W_p + (size_t)w * 32768 + lane * 8, abuf, B1, acc);

      const float wk = (e == 1 || e == 2) ? 2.0f : 1.0f;
      const float cn = (e < 2) ? hdt : ((e == 2) ? dt : dt6);
#pragma unroll
      for (int i = 0; i < 4; ++i)
#pragma unroll
        for (int j = 0; j < 4; ++j) {
          const int ti = i * 4 + j;
          const int sa = (A0 ^ (i << 5)) + j * 16384;
          float hin[4];
          if (e == 0) {
#pragma unroll
            for (int r = 0; r < 4; ++r) hin[r] = h[ti * 4 + r];
          } else {  // staged h_tmp (bf16) from LDS
            const uint2 hb = *(const uint2*)(abuf + sa);
            hin[0] = bflo(hb.x); hin[1] = bfhi(hb.x);
            hin[2] = bflo(hb.y); hin[3] = bfhi(hb.y);
          }
          float kk[4];
#pragma unroll
          for (int r = 0; r < 4; ++r) {
            const float t = tanh_fast(acc[i][j][r]);
            const float itv = (r & 1) ? bfhi(itp[i * 2 + (r >> 1)])
                                      : bflo(itp[i * 2 + (r >> 1)]);
            kk[r] = (t - hin[r]) * itv;
          }
          float sv[4];
          if (e == 0) {
            sv[0] = kk[0]; sv[1] = kk[1]; sv[2] = kk[2]; sv[3] = kk[3];
          } else {
            const uint32_t s01 = Sp[ti * 2], s23 = Sp[ti * 2 + 1];
            sv[0] = bflo(s01) + wk * kk[0];
            sv[1] = bfhi(s01) + wk * kk[1];
            sv[2] = bflo(s23) + wk * kk[2];
            sv[3] = bfhi(s23) + wk * kk[3];
          }
          if (e < 3) {
            Sp[ti * 2] = f2bf(sv[0]) | (f2bf(sv[1]) << 16);
            Sp[ti * 2 + 1] = f2bf(sv[2]) | (f2bf(sv[3]) << 16);
          }
#pragma unroll
          for (int r = 0; r < 4; ++r) {
            const float nxt =
                h[ti * 4 + r] + cn * ((e == 3) ? sv[r] : kk[r]);
            if (e == 3) h[ti * 4 + r] = nxt;  // RK4 state update
            acc[i][j][r] = nxt;               // staging for LDS write
          }
        }
      __syncthreads();  // all LDS reads (B frags + h_in) complete
#pragma unroll
      for (int i = 0; i < 4; ++i)
#pragma unroll
        for (int j = 0; j < 4; ++j) {
          uint2 pk;
          pk.x = f2bf(acc[i][j][0]) | (f2bf(acc[i][j][1]) << 16);
          pk.y = f2bf(acc[i][j][2]) | (f2bf(acc[i][j][3]) << 16);
          *(uint2*)(abuf + ((A0 ^ (i << 5)) + j * 16384)) = pk;
        }
      __syncthreads();  // next operand visible to all waves
    }
  }

  // ---- head: out = h_T @ Wf^T + bf (A = Wf frags; wave w -> out cols 16w..) --
  {
    const float4 b4 = *(const float4*)(bfh + 16 * w + 4 * q);
    f32x4 a2[4];
#pragma unroll
    for (int j = 0; j < 4; ++j) a2[j] = (f32x4){b4.x, b4.y, b4.z, b4.w};
#pragma unroll
    for (int ks = 0; ks < HID / 32; ++ks) {
      const bf16x8 wf =
          *(const bf16x8*)(Wf_p + (size_t)(w * 16 + ks) * 512 + lane * 8);
      const int ba = (B1 ^ ((ks & 3) << 6)) + ((ks >> 2) << 8);
#pragma unroll
      for (int j = 0; j < 4; ++j) {
        const bf16x8 hf = *(const bf16x8*)(abuf + ba + j * 16384);
        a2[j] = __builtin_amdgcn_mfma_f32_16x16x32_bf16(wf, hf, a2[j], 0, 0, 0);
      }
    }
#pragma unroll
    for (int j = 0; j < 4; ++j) {
      float4 o;
      o.x = a2[j][0]; o.y = a2[j][1]; o.z = a2[j][2]; o.w = a2[j][3];
      *(float4*)(out + (size_t)(row0 + 16 * j + l15) * OUT_DIM + 16 * w +
                 4 * q) = o;
    }
  }
}

// Pack row-major fp32 weight [N][K] into bf16 frag stream (16-row tiles):
// dst[((nt*KSEG + ks)*64 + lane)*8 + j] = W[nt*16 + (lane&15)][ks*32 + (lane>>4)*8 + j]
__global__ void pack_bfrag(const float* __restrict__ src, __bf16* __restrict__ dst,
                           int K, int kslog, int total) {
  const int i = blockIdx.x * blockDim.x + threadIdx.x;
  if (i >= total) return;
  const int j = i & 7;
  const int lane = (i >> 3) & 63;
  const int rem = i >> 9;
  const int ks = rem & ((1 << kslog) - 1);
  const int nt = rem >> kslog;
  const int n = (nt << 4) + (lane & 15);
  const int k = (ks << 5) + ((lane >> 4) << 3) + j;
  dst[i] = (__bf16)src[n * K + k];
}

extern "C" void kernel_launch(void* const* d_in, const int* in_sizes, int n_in,
                              void* d_out, int out_size, void* d_ws, size_t ws_size,
                              hipStream_t stream) {
  const float* x = (const float*)d_in[0];
  const float* Wx = (const float*)d_in[1];
  const float* bx = (const float*)d_in[2];
  const float* W = (const float*)d_in[3];
  const float* U = (const float*)d_in[4];
  const float* b = (const float*)d_in[5];
  const float* tau = (const float*)d_in[6];
  const float* Wf = (const float*)d_in[7];
  const float* bf_ = (const float*)d_in[8];
  float* out = (float*)d_out;

  char* ws = (char*)d_ws;  // 1.375 MB used
  __bf16* W_p = (__bf16*)(ws + 0);
  __bf16* U_p = (__bf16*)(ws + (512 * 1024));
  __bf16* Wx_p = (__bf16*)(ws + (1024 * 1024));
  __bf16* Wf_p = (__bf16*)(ws + (1280 * 1024));

  pack_bfrag<<<(HID * HID) / 256, 256, 0, stream>>>(W, W_p, HID, 4, HID * HID);
  pack_bfrag<<<(HID * HID) / 256, 256, 0, stream>>>(U, U_p, HID, 4, HID * HID);
  pack_bfrag<<<(HID * IN_DIM) / 256, 256, 0, stream>>>(Wx, Wx_p, IN_DIM, 3,
                                                       HID * IN_DIM);
  pack_bfrag<<<(OUT_DIM * HID) / 256, 256, 0, stream>>>(Wf, Wf_p, HID, 4,
                                                        OUT_DIM * HID);

  liq_main<<<32768 / BT, TPB, 0, stream>>>(x, bx, b, tau, bf_, Wx_p, U_p, W_p,
                                           Wf_p, out);
}